// Round 1
// baseline (311.365 us; speedup 1.0000x reference)
//
#include <hip/hip_runtime.h>

#define HID 64
#define CHUNK 1024
#define BLOCK 256
#define NWAVE (BLOCK / 64)          // 4
#define ITERS (CHUNK / BLOCK)       // 4
#define GROUPS (CHUNK / 64)         // 16

// Compute 64 outputs for this lane's token: out[e] = sum_d Wm[e][d] * xr[d].
// Wm is a wave-uniform pointer -> W values come in via scalar loads (SGPRs),
// so each FMA is v_fma_f32 with one SGPR source. 4 rows per iteration so the
// store is a full float4.
__device__ __forceinline__ void compute_rows(const float* __restrict__ Wm,
                                             const float (&xr)[HID],
                                             float4* __restrict__ dst,
                                             bool active)
{
#pragma unroll 1
    for (int eg = 0; eg < 16; ++eg) {
        const float* __restrict__ w0 = Wm + (eg * 4 + 0) * HID;
        const float* __restrict__ w1 = Wm + (eg * 4 + 1) * HID;
        const float* __restrict__ w2 = Wm + (eg * 4 + 2) * HID;
        const float* __restrict__ w3 = Wm + (eg * 4 + 3) * HID;
        float a0 = 0.f, a1 = 0.f, a2 = 0.f, a3 = 0.f;
#pragma unroll
        for (int d = 0; d < HID; ++d) {
            const float xv = xr[d];
            a0 = fmaf(w0[d], xv, a0);
            a1 = fmaf(w1[d], xv, a1);
            a2 = fmaf(w2[d], xv, a2);
            a3 = fmaf(w3[d], xv, a3);
        }
        if (active) dst[eg] = make_float4(a0, a1, a2, a3);
    }
}

__global__ __launch_bounds__(BLOCK) void moe_linear(
    const float* __restrict__ x,
    const float* __restrict__ W,
    const int* __restrict__ mod,
    float* __restrict__ out)
{
    __shared__ unsigned short lidx[CHUNK];     // local partition: position -> local token idx
    __shared__ int s_cnt[NWAVE][ITERS][3];
    __shared__ int s_base[NWAVE][ITERS][3];
    __shared__ int s_b[2];                     // start of segment 1 and segment 2

    const int tid  = threadIdx.x;
    const int wave = tid >> 6;
    const int lane = tid & 63;
    const int chunk0 = blockIdx.x * CHUNK;

    // ---- Phase 1: ballot-based stable ranks per (wave, iter, modality) ----
    int mym[ITERS], myrank[ITERS];
#pragma unroll
    for (int it = 0; it < ITERS; ++it) {
        const int p = it * BLOCK + tid;
        const int m = mod[chunk0 + p];
        const unsigned long long b0 = __ballot(m == 0);
        const unsigned long long b1 = __ballot(m == 1);
        const unsigned long long b2 = __ballot(m == 2);
        const unsigned long long below = (1ull << lane) - 1ull;
        const unsigned long long bm = (m == 0) ? b0 : ((m == 1) ? b1 : b2);
        mym[it]    = m;
        myrank[it] = __popcll(bm & below);
        if (lane == 0) {
            s_cnt[wave][it][0] = __popcll(b0);
            s_cnt[wave][it][1] = __popcll(b1);
            s_cnt[wave][it][2] = __popcll(b2);
        }
    }
    __syncthreads();

    // ---- small serial exclusive scan (modality-major) ----
    if (tid == 0) {
        int run = 0;
        for (int m = 0; m < 3; ++m) {
            if (m) s_b[m - 1] = run;
            for (int w = 0; w < NWAVE; ++w)
                for (int it = 0; it < ITERS; ++it) {
                    s_base[w][it][m] = run;
                    run += s_cnt[w][it][m];
                }
        }
    }
    __syncthreads();

    // ---- scatter local indices into modality-grouped order ----
#pragma unroll
    for (int it = 0; it < ITERS; ++it) {
        const int dst = s_base[wave][it][mym[it]] + myrank[it];
        lidx[dst] = (unsigned short)(it * BLOCK + tid);
    }
    __syncthreads();

    const int b1 = s_b[0];
    const int b2 = s_b[1];

    // ---- Phase 2: GEMV per token, modality-uniform waves ----
    for (int sub = 0; sub < GROUPS / NWAVE; ++sub) {
        const int g = sub * NWAVE + wave;
        const int p = g * 64 + lane;
        const int t = lidx[p];
        const int token = chunk0 + t;
        const int m_lane = (p >= b1) + (p >= b2);

        // load this lane's x row into 64 VGPRs (16x dwordx4)
        float xr[HID];
        const float4* __restrict__ xsrc = (const float4*)(x + (size_t)token * HID);
#pragma unroll
        for (int k = 0; k < HID / 4; ++k)
            *(float4*)&xr[4 * k] = xsrc[k];

        float4* __restrict__ dst = (float4*)(out + (size_t)token * HID);

        const int mf = __builtin_amdgcn_readfirstlane(m_lane);
        if (__all(m_lane == mf)) {
            // fast path: whole wave shares one modality
            compute_rows(W + (size_t)mf * HID * HID, xr, dst, true);
        } else {
            // boundary group: up to 2 (worst 3) masked passes
#pragma unroll 1
            for (int mm = 0; mm < 3; ++mm) {
                if (__any(m_lane == mm)) {
                    compute_rows(W + (size_t)mm * HID * HID, xr, dst, m_lane == mm);
                }
            }
        }
    }
}

extern "C" void kernel_launch(void* const* d_in, const int* in_sizes, int n_in,
                              void* d_out, int out_size, void* d_ws, size_t ws_size,
                              hipStream_t stream) {
    const float* x   = (const float*)d_in[0];
    const float* W   = (const float*)d_in[1];
    const int*   mod = (const int*)d_in[2];
    float*       out = (float*)d_out;

    const int n      = in_sizes[0] / HID;   // number of tokens
    const int blocks = n / CHUNK;           // 1024 for N = 1<<20

    moe_linear<<<blocks, BLOCK, 0, stream>>>(x, W, mod, out);
}

// Round 2
// 184.357 us; speedup vs baseline: 1.6889x; 1.6889x over previous
//
#include <hip/hip_runtime.h>

#define HID 64
#define CHUNK 1024
#define BLOCK 256
#define NWAVE (BLOCK / 64)          // 4
#define ITERS (CHUNK / BLOCK)       // 4
#define GROUPS (CHUNK / 64)         // 16
#define WPAD 72                     // padded row (shorts): 144B stride -> 2-way bank alias only

typedef short short8 __attribute__((ext_vector_type(8)));
typedef float floatx4 __attribute__((ext_vector_type(4)));

// fp32 -> bf16 round-to-nearest-even
__device__ __forceinline__ short bf16rne(float f) {
    unsigned u = __float_as_uint(f);
    u = (u + 0x7FFFu + ((u >> 16) & 1u)) >> 16;
    return (short)u;
}

__global__ __launch_bounds__(BLOCK) void moe_mfma(
    const float* __restrict__ x,
    const float* __restrict__ W,
    const int* __restrict__ mod,
    float* __restrict__ out)
{
    __shared__ unsigned short lidx[CHUNK];   // modality-grouped order -> local token idx
    __shared__ short sW[3][HID][WPAD];       // all 3 weight matrices, bf16
    __shared__ int s_cnt[NWAVE][ITERS][3];
    __shared__ int s_base[NWAVE][ITERS][3];
    __shared__ int s_b[2];                   // start of modality-1 and modality-2 segments

    const int tid   = threadIdx.x;
    const int wave  = tid >> 6;
    const int lane  = tid & 63;
    const int chunk0 = blockIdx.x * CHUNK;

    // ---- Stage W (fp32 global -> bf16 LDS), 3*64*64 = 12288 floats ----
    for (int j = tid; j < 3 * HID * HID / 4; j += BLOCK) {
        float4 v = ((const float4*)W)[j];
        const int f = j * 4;
        const int m = f >> 12;          // 4096 elems per matrix
        const int r = (f >> 6) & 63;
        const int c = f & 63;
        short4 s;
        s.x = bf16rne(v.x); s.y = bf16rne(v.y);
        s.z = bf16rne(v.z); s.w = bf16rne(v.w);
        *(short4*)&sW[m][r][c] = s;     // 8B aligned (c % 4 == 0, 144B row stride)
    }

    // ---- Phase 1: ballot-based stable ranks per (wave, iter, modality) ----
    int mym[ITERS], myrank[ITERS];
#pragma unroll
    for (int it = 0; it < ITERS; ++it) {
        const int p = it * BLOCK + tid;
        const int m = mod[chunk0 + p];
        const unsigned long long g0 = __ballot(m == 0);
        const unsigned long long g1 = __ballot(m == 1);
        const unsigned long long g2 = __ballot(m == 2);
        const unsigned long long below = (1ull << lane) - 1ull;
        const unsigned long long bm = (m == 0) ? g0 : ((m == 1) ? g1 : g2);
        mym[it]    = m;
        myrank[it] = __popcll(bm & below);
        if (lane == 0) {
            s_cnt[wave][it][0] = __popcll(g0);
            s_cnt[wave][it][1] = __popcll(g1);
            s_cnt[wave][it][2] = __popcll(g2);
        }
    }
    __syncthreads();

    if (tid == 0) {
        int run = 0;
        for (int m = 0; m < 3; ++m) {
            if (m) s_b[m - 1] = run;
            for (int w = 0; w < NWAVE; ++w)
                for (int it = 0; it < ITERS; ++it) {
                    s_base[w][it][m] = run;
                    run += s_cnt[w][it][m];
                }
        }
    }
    __syncthreads();

#pragma unroll
    for (int it = 0; it < ITERS; ++it) {
        const int dst = s_base[wave][it][mym[it]] + myrank[it];
        lidx[dst] = (unsigned short)(it * BLOCK + tid);
    }
    __syncthreads();

    const int bnd1 = __builtin_amdgcn_readfirstlane(s_b[0]);
    const int bnd2 = __builtin_amdgcn_readfirstlane(s_b[1]);

    // ---- Phase 2: MFMA. Each wave owns 16 output columns for all 16 groups ----
    const int r15 = lane & 15;          // A row / C col within tile
    const int kg  = lane >> 4;          // k-group (0..3)
    const int col = wave * 16 + r15;    // output column this lane produces

    for (int g = 0; g < GROUPS; ++g) {
        const int g64 = g * 64;

        // A-fragments: 4 M-tiles x 2 K-chunks; lane holds x[token(r15)][k..k+7] as bf16
        short8 a[4][2];
#pragma unroll
        for (int mt = 0; mt < 4; ++mt) {
            const int tA = lidx[g64 + mt * 16 + r15];
            const float* xp = x + (size_t)(chunk0 + tA) * HID + kg * 8;
#pragma unroll
            for (int kc = 0; kc < 2; ++kc) {
                const float4 f0 = *(const float4*)(xp + kc * 32);
                const float4 f1 = *(const float4*)(xp + kc * 32 + 4);
                short8 af;
                af[0] = bf16rne(f0.x); af[1] = bf16rne(f0.y);
                af[2] = bf16rne(f0.z); af[3] = bf16rne(f0.w);
                af[4] = bf16rne(f1.x); af[5] = bf16rne(f1.y);
                af[6] = bf16rne(f1.z); af[7] = bf16rne(f1.w);
                a[mt][kc] = af;
            }
        }

        // modality of first/last token in this group (wave-uniform)
        const int m_lo = (g64 >= bnd1) + (g64 >= bnd2);
        const int m_hi = (g64 + 63 >= bnd1) + (g64 + 63 >= bnd2);

        for (int mm = m_lo; mm <= m_hi; ++mm) {
            // B-fragments: B[k][n] = W[n][k]; lane reads 8 consecutive k of W row `col`
            const short8 bf0 = *(const short8*)&sW[mm][col][kg * 8];        // kc=0
            const short8 bf1 = *(const short8*)&sW[mm][col][32 + kg * 8];   // kc=1

            floatx4 acc[4];
#pragma unroll
            for (int mt = 0; mt < 4; ++mt) {
                acc[mt] = (floatx4){0.f, 0.f, 0.f, 0.f};
                acc[mt] = __builtin_amdgcn_mfma_f32_16x16x32_bf16(a[mt][0], bf0, acc[mt], 0, 0, 0);
                acc[mt] = __builtin_amdgcn_mfma_f32_16x16x32_bf16(a[mt][1], bf1, acc[mt], 0, 0, 0);
            }

            // C/D layout: col = lane&15, row = (lane>>4)*4 + reg   [m89-verified]
#pragma unroll
            for (int mt = 0; mt < 4; ++mt) {
#pragma unroll
                for (int rg = 0; rg < 4; ++rg) {
                    const int prow = g64 + mt * 16 + kg * 4 + rg;
                    const int mrow = (prow >= bnd1) + (prow >= bnd2);
                    if (mrow == mm) {
                        const int tok = lidx[prow];
                        out[(size_t)(chunk0 + tok) * HID + col] = acc[mt][rg];
                    }
                }
            }
        }
    }
}

extern "C" void kernel_launch(void* const* d_in, const int* in_sizes, int n_in,
                              void* d_out, int out_size, void* d_ws, size_t ws_size,
                              hipStream_t stream) {
    const float* x   = (const float*)d_in[0];
    const float* W   = (const float*)d_in[1];
    const int*   mod = (const int*)d_in[2];
    float*       out = (float*)d_out;

    const int n      = in_sizes[0] / HID;   // tokens
    const int blocks = n / CHUNK;           // 1024 for N = 1<<20

    moe_mfma<<<blocks, BLOCK, 0, stream>>>(x, W, mod, out);
}

// Round 3
// 176.562 us; speedup vs baseline: 1.7635x; 1.0442x over previous
//
#include <hip/hip_runtime.h>

#define HID 64
#define BLOCK 256
#define GPB 4                        // 64-token groups per block -> 4096 blocks

typedef short short8 __attribute__((ext_vector_type(8)));
typedef float floatx4 __attribute__((ext_vector_type(4)));

// pack two fp32 -> bf16 (RNE) into one u32 (lo in [15:0], hi in [31:16])
__device__ __forceinline__ unsigned bf16rne2(float lo, float hi) {
    unsigned ul = __float_as_uint(lo);
    unsigned uh = __float_as_uint(hi);
    ul = (ul + 0x7FFFu + ((ul >> 16) & 1u)) >> 16;
    uh = (uh + 0x7FFFu + ((uh >> 16) & 1u));
    return ul | (uh & 0xFFFF0000u);
}

// load 8 consecutive fp32 and convert to a bf16 short8 fragment
__device__ __forceinline__ short8 cvt8(const float* __restrict__ p) {
    const float4 f0 = *(const float4*)p;
    const float4 f1 = *(const float4*)(p + 4);
    union { unsigned u[4]; short8 s; } r;
    r.u[0] = bf16rne2(f0.x, f0.y);
    r.u[1] = bf16rne2(f0.z, f0.w);
    r.u[2] = bf16rne2(f1.x, f1.y);
    r.u[3] = bf16rne2(f1.z, f1.w);
    return r.s;
}

__global__ __launch_bounds__(BLOCK) void moe_all3(
    const float* __restrict__ x,
    const float* __restrict__ W,
    const int* __restrict__ mod,
    float* __restrict__ out)
{
    const int tid  = threadIdx.x;
    const int wave = tid >> 6;
    const int lane = tid & 63;
    const int r15  = lane & 15;      // A row / D col-token index within tile
    const int kg   = lane >> 4;      // k-group 0..3

    // ---- A-fragments = W rows (output cols), all 3 modalities, hoisted ----
    // lane holds W[wave*16 + r15][kg*8 .. +8) for kc=0, +32 for kc=1
    short8 wa[3][2];
#pragma unroll
    for (int mm = 0; mm < 3; ++mm) {
        const float* wp = W + (size_t)mm * HID * HID + (size_t)(wave * 16 + r15) * HID + kg * 8;
        wa[mm][0] = cvt8(wp);
        wa[mm][1] = cvt8(wp + 32);
    }

    const int base = blockIdx.x * (GPB * 64);

#pragma unroll 1
    for (int g = 0; g < GPB; ++g) {
#pragma unroll
        for (int mt = 0; mt < 4; ++mt) {
            const int tb    = base + g * 64 + mt * 16;
            const int token = tb + r15;

            // B-fragments = x row of this lane's token (col=r15 -> token)
            const float* xp = x + (size_t)token * HID + kg * 8;
            const short8 xb0 = cvt8(xp);
            const short8 xb1 = cvt8(xp + 32);

            const int m = mod[token];

            floatx4 a0 = {0.f, 0.f, 0.f, 0.f};
            floatx4 a1 = {0.f, 0.f, 0.f, 0.f};
            floatx4 a2 = {0.f, 0.f, 0.f, 0.f};
            a0 = __builtin_amdgcn_mfma_f32_16x16x32_bf16(wa[0][0], xb0, a0, 0, 0, 0);
            a0 = __builtin_amdgcn_mfma_f32_16x16x32_bf16(wa[0][1], xb1, a0, 0, 0, 0);
            a1 = __builtin_amdgcn_mfma_f32_16x16x32_bf16(wa[1][0], xb0, a1, 0, 0, 0);
            a1 = __builtin_amdgcn_mfma_f32_16x16x32_bf16(wa[1][1], xb1, a1, 0, 0, 0);
            a2 = __builtin_amdgcn_mfma_f32_16x16x32_bf16(wa[2][0], xb0, a2, 0, 0, 0);
            a2 = __builtin_amdgcn_mfma_f32_16x16x32_bf16(wa[2][1], xb1, a2, 0, 0, 0);

            // per-lane select: this lane's 4 outputs all belong to `token`
            const floatx4 v = (m == 0) ? a0 : ((m == 1) ? a1 : a2);

            // D: col(lane&15)=token, row(kg*4+reg)=output col within wave's 16
            // -> 4 consecutive floats of out[token]: one dwordx4 store
            *(floatx4*)(out + (size_t)token * HID + wave * 16 + kg * 4) = v;
        }
    }
}

extern "C" void kernel_launch(void* const* d_in, const int* in_sizes, int n_in,
                              void* d_out, int out_size, void* d_ws, size_t ws_size,
                              hipStream_t stream) {
    const float* x   = (const float*)d_in[0];
    const float* W   = (const float*)d_in[1];
    const int*   mod = (const int*)d_in[2];
    float*       out = (float*)d_out;

    const int n      = in_sizes[0] / HID;     // tokens (1<<20)
    const int blocks = n / (GPB * 64);        // 4096

    moe_all3<<<blocks, BLOCK, 0, stream>>>(x, W, mod, out);
}